// Round 1
// baseline (1339.676 us; speedup 1.0000x reference)
//
#include <hip/hip_runtime.h>

#define NN   100000
#define FIN  64
#define HID  32
#define NCLS 10

// ---------------------------------------------------------------------------
// deg[r] += 1 for every non-self-loop edge (segment_sum of ew over row)
// ---------------------------------------------------------------------------
__global__ void deg_kernel(const int* __restrict__ row, const int* __restrict__ col,
                           int* __restrict__ deg, int E) {
    int stride = gridDim.x * blockDim.x;
    for (int e = blockIdx.x * blockDim.x + threadIdx.x; e < E; e += stride) {
        int r = row[e], c = col[e];
        if (r != c) atomicAdd(&deg[r], 1);
    }
}

// ---------------------------------------------------------------------------
// w[e] = (r==c) ? 0 : -(dis[r]*dis[c]),  dis[i] = deg>0 ? rsqrt(deg) : 0
// ---------------------------------------------------------------------------
__global__ void w_kernel(const int* __restrict__ row, const int* __restrict__ col,
                         const int* __restrict__ deg, float* __restrict__ w, int E) {
    int stride = gridDim.x * blockDim.x;
    for (int e = blockIdx.x * blockDim.x + threadIdx.x; e < E; e += stride) {
        int r = row[e], c = col[e];
        int dr = deg[r], dc = deg[c];
        float wr = dr > 0 ? rsqrtf((float)dr) : 0.f;
        float wc = dc > 0 ? rsqrtf((float)dc) : 0.f;
        w[e] = (r == c) ? 0.f : -(wr * wc);
    }
}

// ---------------------------------------------------------------------------
// Tx[col] += w * x[row]  for F=64 features: one wave per edge, lane = feature.
// Gather (256B) and atomic (256B) are both fully coalesced.
// ---------------------------------------------------------------------------
__global__ void scatter64_kernel(const int* __restrict__ row, const int* __restrict__ col,
                                 const float* __restrict__ w, const float* __restrict__ x,
                                 float* __restrict__ out, int E) {
    int lane = threadIdx.x & 63;
    int wid  = (blockIdx.x * blockDim.x + threadIdx.x) >> 6;
    int nw   = (gridDim.x * blockDim.x) >> 6;
    for (int e = wid; e < E; e += nw) {
        float we = w[e];
        if (we != 0.f) {
            int r = row[e];
            int c = col[e];
            atomicAdd(&out[(size_t)c * FIN + lane], we * x[(size_t)r * FIN + lane]);
        }
    }
}

// ---------------------------------------------------------------------------
// Same for F=32: two edges per wave (lanes 0-31 edge A, lanes 32-63 edge B).
// ---------------------------------------------------------------------------
__global__ void scatter32_kernel(const int* __restrict__ row, const int* __restrict__ col,
                                 const float* __restrict__ w, const float* __restrict__ h,
                                 float* __restrict__ out, int E) {
    int lane = threadIdx.x & 63;
    int sub  = lane >> 5;        // which edge of the pair
    int f    = lane & 31;        // feature
    int gw   = (blockIdx.x * blockDim.x + threadIdx.x) >> 6;
    int nw   = (gridDim.x * blockDim.x) >> 6;
    for (int e = gw * 2 + sub; e < E; e += nw * 2) {
        float we = w[e];
        if (we != 0.f) {
            int r = row[e], c = col[e];
            atomicAdd(&out[(size_t)c * HID + f], we * h[(size_t)r * HID + f]);
        }
    }
}

// ---------------------------------------------------------------------------
// h = relu(x @ W0 + Tx1 @ W1 + b)   [NN,64]x[64,32]
// One thread per node; 32 accumulators in VGPRs; W loads are wave-uniform so
// the compiler emits s_load (SGPR operand into v_fmac).
// ---------------------------------------------------------------------------
__global__ __launch_bounds__(256) void layer1_kernel(
        const float* __restrict__ x, const float* __restrict__ tx,
        const float* __restrict__ W0, const float* __restrict__ W1,
        const float* __restrict__ b, float* __restrict__ h_out) {
    int n = blockIdx.x * blockDim.x + threadIdx.x;
    if (n >= NN) return;
    float acc[HID];
#pragma unroll
    for (int j = 0; j < HID; ++j) acc[j] = b[j];
    const float4* xr = (const float4*)(x  + (size_t)n * FIN);
    const float4* tr = (const float4*)(tx + (size_t)n * FIN);
    for (int k4 = 0; k4 < FIN / 4; ++k4) {
        float4 xv = xr[k4];
        float4 tv = tr[k4];
        float xs[4] = {xv.x, xv.y, xv.z, xv.w};
        float ts[4] = {tv.x, tv.y, tv.z, tv.w};
#pragma unroll
        for (int kk = 0; kk < 4; ++kk) {
            const float* w0r = W0 + (k4 * 4 + kk) * HID;
            const float* w1r = W1 + (k4 * 4 + kk) * HID;
#pragma unroll
            for (int j = 0; j < HID; ++j)
                acc[j] += xs[kk] * w0r[j] + ts[kk] * w1r[j];
        }
    }
    float4* dst = (float4*)(h_out + (size_t)n * HID);
#pragma unroll
    for (int j4 = 0; j4 < HID / 4; ++j4) {
        float4 v;
        v.x = fmaxf(acc[j4 * 4 + 0], 0.f);
        v.y = fmaxf(acc[j4 * 4 + 1], 0.f);
        v.z = fmaxf(acc[j4 * 4 + 2], 0.f);
        v.w = fmaxf(acc[j4 * 4 + 3], 0.f);
        dst[j4] = v;
    }
}

// ---------------------------------------------------------------------------
// out = log_softmax(h @ W0 + Tx2 @ W1 + b)   [NN,32]x[32,10]
// ---------------------------------------------------------------------------
__global__ __launch_bounds__(256) void layer2_kernel(
        const float* __restrict__ h, const float* __restrict__ tx,
        const float* __restrict__ W0, const float* __restrict__ W1,
        const float* __restrict__ b, float* __restrict__ out) {
    int n = blockIdx.x * blockDim.x + threadIdx.x;
    if (n >= NN) return;
    float acc[NCLS];
#pragma unroll
    for (int j = 0; j < NCLS; ++j) acc[j] = b[j];
    const float4* hr = (const float4*)(h  + (size_t)n * HID);
    const float4* tr = (const float4*)(tx + (size_t)n * HID);
#pragma unroll
    for (int k4 = 0; k4 < HID / 4; ++k4) {
        float4 hv = hr[k4];
        float4 tv = tr[k4];
        float hs[4] = {hv.x, hv.y, hv.z, hv.w};
        float ts[4] = {tv.x, tv.y, tv.z, tv.w};
#pragma unroll
        for (int kk = 0; kk < 4; ++kk) {
            const float* w0r = W0 + (k4 * 4 + kk) * NCLS;
            const float* w1r = W1 + (k4 * 4 + kk) * NCLS;
#pragma unroll
            for (int j = 0; j < NCLS; ++j)
                acc[j] += hs[kk] * w0r[j] + ts[kk] * w1r[j];
        }
    }
    // log_softmax over 10 values in registers
    float m = acc[0];
#pragma unroll
    for (int j = 1; j < NCLS; ++j) m = fmaxf(m, acc[j]);
    float s = 0.f;
#pragma unroll
    for (int j = 0; j < NCLS; ++j) s += expf(acc[j] - m);
    float lse = m + logf(s);
    float* dst = out + (size_t)n * NCLS;
#pragma unroll
    for (int j = 0; j < NCLS; ++j) dst[j] = acc[j] - lse;
}

// ---------------------------------------------------------------------------
extern "C" void kernel_launch(void* const* d_in, const int* in_sizes, int n_in,
                              void* d_out, int out_size, void* d_ws, size_t ws_size,
                              hipStream_t stream) {
    const float* x    = (const float*)d_in[0];
    const int*   ei   = (const int*)d_in[1];
    const float* W0_1 = (const float*)d_in[2];
    const float* W1_1 = (const float*)d_in[3];
    const float* b1   = (const float*)d_in[4];
    const float* W0_2 = (const float*)d_in[5];
    const float* W1_2 = (const float*)d_in[6];
    const float* b2   = (const float*)d_in[7];

    const int E = in_sizes[1] / 2;
    const int* row = ei;
    const int* col = ei + E;

    // workspace layout (floats): [deg NN][w E][tx1 NN*FIN][tx2 NN*HID]
    float* ws  = (float*)d_ws;
    int*   deg = (int*)ws;
    float* w   = ws + NN;
    float* tx1 = w + E;
    float* tx2 = tx1 + (size_t)NN * FIN;

    // output layout: [log_softmax NN*NCLS][x_latent NN*HID]
    float* out_ls = (float*)d_out;
    float* h      = out_ls + (size_t)NN * NCLS;

    hipMemsetAsync(deg, 0, NN * sizeof(int), stream);
    hipMemsetAsync(tx1, 0, (size_t)NN * FIN * sizeof(float), stream);
    hipMemsetAsync(tx2, 0, (size_t)NN * HID * sizeof(float), stream);

    const int tpb = 256;
    int egrid = (E + tpb - 1) / tpb;
    if (egrid > 4096) egrid = 4096;

    deg_kernel<<<egrid, tpb, 0, stream>>>(row, col, deg, E);
    w_kernel<<<egrid, tpb, 0, stream>>>(row, col, deg, w, E);

    scatter64_kernel<<<8192, 256, 0, stream>>>(row, col, w, x, tx1, E);

    int ngrid = (NN + tpb - 1) / tpb;
    layer1_kernel<<<ngrid, tpb, 0, stream>>>(x, tx1, W0_1, W1_1, b1, h);

    scatter32_kernel<<<8192, 256, 0, stream>>>(row, col, w, h, tx2, E);

    layer2_kernel<<<ngrid, tpb, 0, stream>>>(h, tx2, W0_2, W1_2, b2, out_ls);
}

// Round 2
// 1148.068 us; speedup vs baseline: 1.1669x; 1.1669x over previous
//
#include <hip/hip_runtime.h>

#define NN   100000
#define FIN  64
#define HID  32
#define NCLS 10

// ---------------------------------------------------------------------------
// Histogram: degr[r]++ (normalization degree, over row) and cnt[c]++ (CSR
// bucket sizes, over col) for every non-self-loop edge. Int atomics only.
// ---------------------------------------------------------------------------
__global__ void hist_kernel(const int* __restrict__ row, const int* __restrict__ col,
                            int* __restrict__ degr, int* __restrict__ cnt, int E) {
    int stride = gridDim.x * blockDim.x;
    for (int e = blockIdx.x * blockDim.x + threadIdx.x; e < E; e += stride) {
        int r = row[e], c = col[e];
        if (r != c) {
            atomicAdd(&degr[r], 1);
            atomicAdd(&cnt[c], 1);
        }
    }
}

// ---------------------------------------------------------------------------
// dis[i] = deg>0 ? rsqrt(deg) : 0
// ---------------------------------------------------------------------------
__global__ void dis_kernel(const int* __restrict__ degr, float* __restrict__ dis) {
    int i = blockIdx.x * blockDim.x + threadIdx.x;
    if (i < NN) {
        int d = degr[i];
        dis[i] = d > 0 ? rsqrtf((float)d) : 0.f;
    }
}

// ---------------------------------------------------------------------------
// Exclusive scan of cnt[NN] -> colptr[NN+1], plus a working copy in cursor.
// Single block of 1024 threads, 98 elements each.
// ---------------------------------------------------------------------------
#define SCAN_T 1024
#define CHUNK  98   // ceil(100000/1024)
__global__ __launch_bounds__(SCAN_T) void scan_kernel(const int* __restrict__ cnt,
                                                      int* __restrict__ colptr,
                                                      int* __restrict__ cursor) {
    __shared__ int part[SCAN_T];
    int t = threadIdx.x;
    int base = t * CHUNK;
    int s = 0;
    for (int j = 0; j < CHUNK; ++j) {
        int i = base + j;
        if (i < NN) s += cnt[i];
    }
    part[t] = s;
    __syncthreads();
    for (int off = 1; off < SCAN_T; off <<= 1) {
        int v = (t >= off) ? part[t - off] : 0;
        __syncthreads();
        part[t] += v;
        __syncthreads();
    }
    int run = part[t] - s;  // exclusive prefix of this thread's chunk
    for (int j = 0; j < CHUNK; ++j) {
        int i = base + j;
        if (i < NN) {
            colptr[i] = run;
            cursor[i] = run;
            run += cnt[i];
        }
    }
    if (t == SCAN_T - 1) colptr[NN] = part[SCAN_T - 1];
}

// ---------------------------------------------------------------------------
// Placement: bucket source row of each non-self-loop edge by destination col.
// ---------------------------------------------------------------------------
__global__ void place_kernel(const int* __restrict__ row, const int* __restrict__ col,
                             int* __restrict__ cursor, int* __restrict__ srow, int E) {
    int stride = gridDim.x * blockDim.x;
    for (int e = blockIdx.x * blockDim.x + threadIdx.x; e < E; e += stride) {
        int r = row[e], c = col[e];
        if (r != c) {
            int p = atomicAdd(&cursor[c], 1);
            srow[p] = r;
        }
    }
}

// ---------------------------------------------------------------------------
// Tx1[c] = -dis[c] * sum_{r in N(c)} dis[r] * x[r]   (F=64, one wave/node,
// lane = feature). Coalesced 256B gathers, register accumulation, 4-way ILP,
// single 256B store per node. No fp32 atomics.
// ---------------------------------------------------------------------------
__global__ __launch_bounds__(256) void gather64_kernel(
        const int* __restrict__ colptr, const int* __restrict__ srow,
        const float* __restrict__ dis, const float* __restrict__ x,
        float* __restrict__ tx) {
    int lane = threadIdx.x & 63;
    int c = __builtin_amdgcn_readfirstlane(blockIdx.x * 4 + (threadIdx.x >> 6));
    if (c >= NN) return;
    int start = colptr[c], end = colptr[c + 1];
    float dc = dis[c];
    float a0 = 0.f, a1 = 0.f, a2 = 0.f, a3 = 0.f;
    int i = start;
    for (; i + 4 <= end; i += 4) {
        int r0 = srow[i], r1 = srow[i + 1], r2 = srow[i + 2], r3 = srow[i + 3];
        float w0 = dis[r0], w1 = dis[r1], w2 = dis[r2], w3 = dis[r3];
        a0 += w0 * x[(size_t)r0 * FIN + lane];
        a1 += w1 * x[(size_t)r1 * FIN + lane];
        a2 += w2 * x[(size_t)r2 * FIN + lane];
        a3 += w3 * x[(size_t)r3 * FIN + lane];
    }
    for (; i < end; ++i) {
        int r = srow[i];
        a0 += dis[r] * x[(size_t)r * FIN + lane];
    }
    tx[(size_t)c * FIN + lane] = -dc * (a0 + a1 + a2 + a3);
}

// ---------------------------------------------------------------------------
// Same for F=32: one wave/node, two edges in flight per iteration
// (lanes 0-31 = even edge slot, lanes 32-63 = odd edge slot), combined at the
// end with a cross-half shuffle.
// ---------------------------------------------------------------------------
__global__ __launch_bounds__(256) void gather32_kernel(
        const int* __restrict__ colptr, const int* __restrict__ srow,
        const float* __restrict__ dis, const float* __restrict__ h,
        float* __restrict__ tx) {
    int lane = threadIdx.x & 63;
    int sub  = lane >> 5;
    int f    = lane & 31;
    int c = __builtin_amdgcn_readfirstlane(blockIdx.x * 4 + (threadIdx.x >> 6));
    if (c >= NN) return;
    int start = colptr[c], end = colptr[c + 1];
    float dc = dis[c];
    float a0 = 0.f, a1 = 0.f;
    int i = start + sub;
    for (; i + 2 < end; i += 4) {
        int r0 = srow[i], r1 = srow[i + 2];
        a0 += dis[r0] * h[(size_t)r0 * HID + f];
        a1 += dis[r1] * h[(size_t)r1 * HID + f];
    }
    for (; i < end; i += 2) {
        int r = srow[i];
        a0 += dis[r] * h[(size_t)r * HID + f];
    }
    float tot = a0 + a1;
    tot += __shfl_xor(tot, 32);
    if (lane < 32) tx[(size_t)c * HID + f] = -dc * tot;
}

// ---------------------------------------------------------------------------
// h = relu(x @ W0 + Tx1 @ W1 + b)   [NN,64]x[64,32]
// ---------------------------------------------------------------------------
__global__ __launch_bounds__(256) void layer1_kernel(
        const float* __restrict__ x, const float* __restrict__ tx,
        const float* __restrict__ W0, const float* __restrict__ W1,
        const float* __restrict__ b, float* __restrict__ h_out) {
    int n = blockIdx.x * blockDim.x + threadIdx.x;
    if (n >= NN) return;
    float acc[HID];
#pragma unroll
    for (int j = 0; j < HID; ++j) acc[j] = b[j];
    const float4* xr = (const float4*)(x  + (size_t)n * FIN);
    const float4* tr = (const float4*)(tx + (size_t)n * FIN);
    for (int k4 = 0; k4 < FIN / 4; ++k4) {
        float4 xv = xr[k4];
        float4 tv = tr[k4];
        float xs[4] = {xv.x, xv.y, xv.z, xv.w};
        float ts[4] = {tv.x, tv.y, tv.z, tv.w};
#pragma unroll
        for (int kk = 0; kk < 4; ++kk) {
            const float* w0r = W0 + (k4 * 4 + kk) * HID;
            const float* w1r = W1 + (k4 * 4 + kk) * HID;
#pragma unroll
            for (int j = 0; j < HID; ++j)
                acc[j] += xs[kk] * w0r[j] + ts[kk] * w1r[j];
        }
    }
    float4* dst = (float4*)(h_out + (size_t)n * HID);
#pragma unroll
    for (int j4 = 0; j4 < HID / 4; ++j4) {
        float4 v;
        v.x = fmaxf(acc[j4 * 4 + 0], 0.f);
        v.y = fmaxf(acc[j4 * 4 + 1], 0.f);
        v.z = fmaxf(acc[j4 * 4 + 2], 0.f);
        v.w = fmaxf(acc[j4 * 4 + 3], 0.f);
        dst[j4] = v;
    }
}

// ---------------------------------------------------------------------------
// out = log_softmax(h @ W0 + Tx2 @ W1 + b)   [NN,32]x[32,10]
// ---------------------------------------------------------------------------
__global__ __launch_bounds__(256) void layer2_kernel(
        const float* __restrict__ h, const float* __restrict__ tx,
        const float* __restrict__ W0, const float* __restrict__ W1,
        const float* __restrict__ b, float* __restrict__ out) {
    int n = blockIdx.x * blockDim.x + threadIdx.x;
    if (n >= NN) return;
    float acc[NCLS];
#pragma unroll
    for (int j = 0; j < NCLS; ++j) acc[j] = b[j];
    const float4* hr = (const float4*)(h  + (size_t)n * HID);
    const float4* tr = (const float4*)(tx + (size_t)n * HID);
#pragma unroll
    for (int k4 = 0; k4 < HID / 4; ++k4) {
        float4 hv = hr[k4];
        float4 tv = tr[k4];
        float hs[4] = {hv.x, hv.y, hv.z, hv.w};
        float ts[4] = {tv.x, tv.y, tv.z, tv.w};
#pragma unroll
        for (int kk = 0; kk < 4; ++kk) {
            const float* w0r = W0 + (k4 * 4 + kk) * NCLS;
            const float* w1r = W1 + (k4 * 4 + kk) * NCLS;
#pragma unroll
            for (int j = 0; j < NCLS; ++j)
                acc[j] += hs[kk] * w0r[j] + ts[kk] * w1r[j];
        }
    }
    float m = acc[0];
#pragma unroll
    for (int j = 1; j < NCLS; ++j) m = fmaxf(m, acc[j]);
    float s = 0.f;
#pragma unroll
    for (int j = 0; j < NCLS; ++j) s += expf(acc[j] - m);
    float lse = m + logf(s);
    float* dst = out + (size_t)n * NCLS;
#pragma unroll
    for (int j = 0; j < NCLS; ++j) dst[j] = acc[j] - lse;
}

// ---------------------------------------------------------------------------
extern "C" void kernel_launch(void* const* d_in, const int* in_sizes, int n_in,
                              void* d_out, int out_size, void* d_ws, size_t ws_size,
                              hipStream_t stream) {
    const float* x    = (const float*)d_in[0];
    const int*   ei   = (const int*)d_in[1];
    const float* W0_1 = (const float*)d_in[2];
    const float* W1_1 = (const float*)d_in[3];
    const float* b1   = (const float*)d_in[4];
    const float* W0_2 = (const float*)d_in[5];
    const float* W1_2 = (const float*)d_in[6];
    const float* b2   = (const float*)d_in[7];

    const int E = in_sizes[1] / 2;
    const int* row = ei;
    const int* col = ei + E;

    // workspace layout (4B units, all offsets kept 16B-aligned):
    // [degr NN][cnt NN][colptr NN+4][cursor NN][srow E][dis NN][tx1 64*NN]
    // tx2 aliases tx1 (tx1 is dead after layer1).
    int*   degr   = (int*)d_ws;
    int*   cnt    = degr + NN;
    int*   colptr = cnt + NN;          // NN+1 used, NN+4 reserved
    int*   cursor = colptr + NN + 4;
    int*   srow   = cursor + NN;       // E
    float* dis    = (float*)(srow + E);
    float* tx1    = dis + NN;
    float* tx2    = tx1;               // alias: gather32 runs after layer1

    // output layout: [log_softmax NN*NCLS][x_latent NN*HID]
    float* out_ls = (float*)d_out;
    float* h      = out_ls + (size_t)NN * NCLS;

    hipMemsetAsync(degr, 0, 2 * NN * sizeof(int), stream);  // degr + cnt

    const int tpb = 256;
    int egrid = (E + tpb - 1) / tpb;

    hist_kernel<<<egrid, tpb, 0, stream>>>(row, col, degr, cnt, E);
    scan_kernel<<<1, SCAN_T, 0, stream>>>(cnt, colptr, cursor);
    dis_kernel<<<(NN + tpb - 1) / tpb, tpb, 0, stream>>>(degr, dis);
    place_kernel<<<egrid, tpb, 0, stream>>>(row, col, cursor, srow, E);

    int ggrid = (NN + 3) / 4;  // 4 waves (nodes) per 256-thread block
    gather64_kernel<<<ggrid, tpb, 0, stream>>>(colptr, srow, dis, x, tx1);

    int ngrid = (NN + tpb - 1) / tpb;
    layer1_kernel<<<ngrid, tpb, 0, stream>>>(x, tx1, W0_1, W1_1, b1, h);

    gather32_kernel<<<ggrid, tpb, 0, stream>>>(colptr, srow, dis, h, tx2);

    layer2_kernel<<<ngrid, tpb, 0, stream>>>(h, tx2, W0_2, W1_2, b2, out_ls);
}

// Round 3
// 541.364 us; speedup vs baseline: 2.4746x; 2.1207x over previous
//
#include <hip/hip_runtime.h>

#define NN   100000
#define FIN  64
#define HID  32
#define NCLS 10
#define BW   256                    // destinations per bucket
#define NB   391                    // ceil(NN/BW)

// ---------------------------------------------------------------------------
// Pass A: degr[r]++ (row-degree for normalization) + per-block LDS histogram
// of destination buckets (c>>8), flushed to global btot.
// ---------------------------------------------------------------------------
__global__ __launch_bounds__(256) void histA_kernel(
        const int* __restrict__ row, const int* __restrict__ col,
        int* __restrict__ degr, int* __restrict__ btot, int E) {
    __shared__ int lh[NB];
    for (int t = threadIdx.x; t < NB; t += 256) lh[t] = 0;
    __syncthreads();
    int stride = gridDim.x * 256;
    for (int e = blockIdx.x * 256 + threadIdx.x; e < E; e += stride) {
        int r = row[e], c = col[e];
        if (r != c) {
            atomicAdd(&degr[r], 1);
            atomicAdd(&lh[c >> 8], 1);
        }
    }
    __syncthreads();
    for (int t = threadIdx.x; t < NB; t += 256) {
        int v = lh[t];
        if (v) atomicAdd(&btot[t], v);
    }
}

// ---------------------------------------------------------------------------
// Exclusive scan over NB bucket totals -> bptr / bcursor; also colptr[NN].
// ---------------------------------------------------------------------------
__global__ __launch_bounds__(512) void bscan_kernel(
        const int* __restrict__ btot, int* __restrict__ bptr,
        int* __restrict__ bcursor, int* __restrict__ colptr) {
    __shared__ int sh[512];
    int t = threadIdx.x;
    int own = (t < NB) ? btot[t] : 0;
    sh[t] = own;
    __syncthreads();
    for (int off = 1; off < 512; off <<= 1) {
        int v = (t >= off) ? sh[t - off] : 0;
        __syncthreads();
        sh[t] += v;
        __syncthreads();
    }
    int excl = sh[t] - own;
    if (t < NB) { bptr[t] = excl; bcursor[t] = excl; }
    if (t == 511) { bptr[NB] = sh[511]; colptr[NN] = sh[511]; }
}

// ---------------------------------------------------------------------------
// dis[i] = deg>0 ? rsqrt(deg) : 0
// ---------------------------------------------------------------------------
__global__ void dis_kernel(const int* __restrict__ degr, float* __restrict__ dis) {
    int i = blockIdx.x * blockDim.x + threadIdx.x;
    if (i < NN) {
        int d = degr[i];
        dis[i] = d > 0 ? rsqrtf((float)d) : 0.f;
    }
}

// ---------------------------------------------------------------------------
// Pass B: each block owns a contiguous edge chunk; local bucket histogram,
// one global cursor atomic per (block,bucket) to reserve a contiguous run,
// then write (r,c) pairs into the run. Each ~128B run is written by exactly
// one block -> no cross-XCD cacheline bouncing.
// ---------------------------------------------------------------------------
__global__ __launch_bounds__(256) void bucket_kernel(
        const int* __restrict__ row, const int* __restrict__ col,
        int* __restrict__ bcursor, int2* __restrict__ pairs, int E, int chunk) {
    __shared__ int lh[NB];
    __shared__ int lcur[NB];
    for (int t = threadIdx.x; t < NB; t += 256) lh[t] = 0;
    __syncthreads();
    int base = blockIdx.x * chunk;
    int lim = base + chunk; if (lim > E) lim = E;
    for (int e = base + threadIdx.x; e < lim; e += 256) {
        int r = row[e], c = col[e];
        if (r != c) atomicAdd(&lh[c >> 8], 1);
    }
    __syncthreads();
    for (int t = threadIdx.x; t < NB; t += 256) {
        int v = lh[t];
        lcur[t] = v ? atomicAdd(&bcursor[t], v) : 0;
    }
    __syncthreads();
    for (int e = base + threadIdx.x; e < lim; e += 256) {
        int r = row[e], c = col[e];
        if (r != c) {
            int p = atomicAdd(&lcur[c >> 8], 1);
            pairs[p] = make_int2(r, c);
        }
    }
}

// ---------------------------------------------------------------------------
// Per-bucket placement: one block per bucket. LDS histogram + scan over the
// bucket's 256 destinations produces colptr for free; srow writes land in a
// ~32KB window resident in this block's L2.
// ---------------------------------------------------------------------------
__global__ __launch_bounds__(256) void place2_kernel(
        const int2* __restrict__ pairs, const int* __restrict__ bptr,
        int* __restrict__ colptr, int* __restrict__ srow) {
    __shared__ int lh[BW];
    __shared__ int incl[BW];
    __shared__ int lcur[BW];
    int b = blockIdx.x;
    int t = threadIdx.x;
    int start = bptr[b], end = bptr[b + 1];
    int dbase = b << 8;
    lh[t] = 0;
    __syncthreads();
    for (int i = start + t; i < end; i += 256)
        atomicAdd(&lh[pairs[i].y - dbase], 1);
    __syncthreads();
    int own = lh[t];
    incl[t] = own;
    __syncthreads();
    for (int off = 1; off < 256; off <<= 1) {
        int v = (t >= off) ? incl[t - off] : 0;
        __syncthreads();
        incl[t] += v;
        __syncthreads();
    }
    int excl = start + incl[t] - own;
    int d = dbase + t;
    if (d < NN) colptr[d] = excl;
    lcur[t] = excl;
    __syncthreads();
    for (int i = start + t; i < end; i += 256) {
        int2 p = pairs[i];
        int pos = atomicAdd(&lcur[p.y - dbase], 1);
        srow[pos] = p.x;
    }
}

// ---------------------------------------------------------------------------
// mm1: xw0 = x @ W0_1 + b1   and   y1 = dis[n] * (x @ W1_1)    [NN,64]->[NN,32]x2
// ---------------------------------------------------------------------------
__global__ __launch_bounds__(256) void mm1_kernel(
        const float* __restrict__ x, const float* __restrict__ dis,
        const float* __restrict__ W0, const float* __restrict__ W1,
        const float* __restrict__ b1, float* __restrict__ xw0,
        float* __restrict__ y1) {
    int n = blockIdx.x * 256 + threadIdx.x;
    if (n >= NN) return;
    float acc0[HID], acc1[HID];
#pragma unroll
    for (int j = 0; j < HID; ++j) { acc0[j] = b1[j]; acc1[j] = 0.f; }
    const float4* xr = (const float4*)(x + (size_t)n * FIN);
    for (int k4 = 0; k4 < FIN / 4; ++k4) {
        float4 xv = xr[k4];
        float xs[4] = {xv.x, xv.y, xv.z, xv.w};
#pragma unroll
        for (int kk = 0; kk < 4; ++kk) {
            const float* w0r = W0 + (k4 * 4 + kk) * HID;
            const float* w1r = W1 + (k4 * 4 + kk) * HID;
#pragma unroll
            for (int j = 0; j < HID; ++j) {
                acc0[j] += xs[kk] * w0r[j];
                acc1[j] += xs[kk] * w1r[j];
            }
        }
    }
    float dn = dis[n];
    float4* d0 = (float4*)(xw0 + (size_t)n * HID);
    float4* d1 = (float4*)(y1 + (size_t)n * HID);
#pragma unroll
    for (int j4 = 0; j4 < HID / 4; ++j4) {
        d0[j4] = make_float4(acc0[j4*4], acc0[j4*4+1], acc0[j4*4+2], acc0[j4*4+3]);
        d1[j4] = make_float4(dn*acc1[j4*4], dn*acc1[j4*4+1], dn*acc1[j4*4+2], dn*acc1[j4*4+3]);
    }
}

// ---------------------------------------------------------------------------
// gatherH: h[c] = relu(xw0[c] - dis[c] * sum_{r in N(c)} y1[r])
// One wave per node; 2 edge slots x 32 features; ILP 2.
// ---------------------------------------------------------------------------
__global__ __launch_bounds__(256) void gatherH_kernel(
        const int* __restrict__ colptr, const int* __restrict__ srow,
        const float* __restrict__ dis, const float* __restrict__ y1,
        const float* __restrict__ xw0, float* __restrict__ h) {
    int lane = threadIdx.x & 63;
    int sub = lane >> 5, f = lane & 31;
    int c = __builtin_amdgcn_readfirstlane(blockIdx.x * 4 + (threadIdx.x >> 6));
    if (c >= NN) return;
    int start = colptr[c], end = colptr[c + 1];
    float a0 = 0.f, a1 = 0.f;
    int i = start + sub;
    for (; i + 2 < end; i += 4) {
        int r0 = srow[i], r1 = srow[i + 2];
        a0 += y1[(size_t)r0 * HID + f];
        a1 += y1[(size_t)r1 * HID + f];
    }
    for (; i < end; i += 2) a0 += y1[(size_t)srow[i] * HID + f];
    float tot = a0 + a1;
    tot += __shfl_xor(tot, 32);
    if (lane < 32) {
        float v = xw0[(size_t)c * HID + f] - dis[c] * tot;
        h[(size_t)c * HID + f] = fmaxf(v, 0.f);
    }
}

// ---------------------------------------------------------------------------
// mm2: hw0 = h @ W0_2 + b2  [NN,10]  and  y2 = dis[n]*(h @ W1_2) padded to 16
// ---------------------------------------------------------------------------
__global__ __launch_bounds__(256) void mm2_kernel(
        const float* __restrict__ h, const float* __restrict__ dis,
        const float* __restrict__ W0, const float* __restrict__ W1,
        const float* __restrict__ b2, float* __restrict__ hw0,
        float* __restrict__ y2) {
    int n = blockIdx.x * 256 + threadIdx.x;
    if (n >= NN) return;
    float acc0[NCLS], acc1[NCLS];
#pragma unroll
    for (int j = 0; j < NCLS; ++j) { acc0[j] = b2[j]; acc1[j] = 0.f; }
    const float4* hr = (const float4*)(h + (size_t)n * HID);
#pragma unroll
    for (int k4 = 0; k4 < HID / 4; ++k4) {
        float4 hv = hr[k4];
        float hs[4] = {hv.x, hv.y, hv.z, hv.w};
#pragma unroll
        for (int kk = 0; kk < 4; ++kk) {
            const float* w0r = W0 + (k4 * 4 + kk) * NCLS;
            const float* w1r = W1 + (k4 * 4 + kk) * NCLS;
#pragma unroll
            for (int j = 0; j < NCLS; ++j) {
                acc0[j] += hs[kk] * w0r[j];
                acc1[j] += hs[kk] * w1r[j];
            }
        }
    }
    float dn = dis[n];
    float* hd = hw0 + (size_t)n * NCLS;
#pragma unroll
    for (int j = 0; j < NCLS; ++j) hd[j] = acc0[j];
    float4* yd = (float4*)(y2 + (size_t)n * 16);
    float v[16];
#pragma unroll
    for (int j = 0; j < NCLS; ++j) v[j] = dn * acc1[j];
#pragma unroll
    for (int j = NCLS; j < 16; ++j) v[j] = 0.f;
#pragma unroll
    for (int j4 = 0; j4 < 4; ++j4)
        yd[j4] = make_float4(v[j4*4], v[j4*4+1], v[j4*4+2], v[j4*4+3]);
}

// ---------------------------------------------------------------------------
// gatherOut: out[c] = log_softmax(hw0[c] - dis[c]*sum y2[r]).
// One wave per node; 4 edge slots x 16 lanes; softmax via in-group shuffles.
// ---------------------------------------------------------------------------
__global__ __launch_bounds__(256) void gatherOut_kernel(
        const int* __restrict__ colptr, const int* __restrict__ srow,
        const float* __restrict__ dis, const float* __restrict__ y2,
        const float* __restrict__ hw0, float* __restrict__ out) {
    int lane = threadIdx.x & 63;
    int sub = lane >> 4, f = lane & 15;
    int c = __builtin_amdgcn_readfirstlane(blockIdx.x * 4 + (threadIdx.x >> 6));
    if (c >= NN) return;
    int start = colptr[c], end = colptr[c + 1];
    float a0 = 0.f, a1 = 0.f;
    int i = start + sub;
    for (; i + 4 < end; i += 8) {
        int r0 = srow[i], r1 = srow[i + 4];
        a0 += y2[(size_t)r0 * 16 + f];
        a1 += y2[(size_t)r1 * 16 + f];
    }
    for (; i < end; i += 4) a0 += y2[(size_t)srow[i] * 16 + f];
    float tot = a0 + a1;
    tot += __shfl_xor(tot, 16);   // combine 4 slots
    tot += __shfl_xor(tot, 32);
    float val = (f < NCLS ? hw0[(size_t)c * NCLS + f] : 0.f) - dis[c] * tot;
    float mv = (f < NCLS) ? val : -INFINITY;
    mv = fmaxf(mv, __shfl_xor(mv, 1));
    mv = fmaxf(mv, __shfl_xor(mv, 2));
    mv = fmaxf(mv, __shfl_xor(mv, 4));
    mv = fmaxf(mv, __shfl_xor(mv, 8));
    float ev = (f < NCLS) ? expf(val - mv) : 0.f;
    ev += __shfl_xor(ev, 1);
    ev += __shfl_xor(ev, 2);
    ev += __shfl_xor(ev, 4);
    ev += __shfl_xor(ev, 8);
    float lse = mv + logf(ev);
    if (lane < 16 && f < NCLS) out[(size_t)c * NCLS + f] = val - lse;
}

// ---------------------------------------------------------------------------
extern "C" void kernel_launch(void* const* d_in, const int* in_sizes, int n_in,
                              void* d_out, int out_size, void* d_ws, size_t ws_size,
                              hipStream_t stream) {
    const float* x    = (const float*)d_in[0];
    const int*   ei   = (const int*)d_in[1];
    const float* W0_1 = (const float*)d_in[2];
    const float* W1_1 = (const float*)d_in[3];
    const float* b1   = (const float*)d_in[4];
    const float* W0_2 = (const float*)d_in[5];
    const float* W1_2 = (const float*)d_in[6];
    const float* b2   = (const float*)d_in[7];

    const int E = in_sizes[1] / 2;
    const int* row = ei;
    const int* col = ei + E;

    // workspace layout (all 16B-aligned):
    // [degr NN][dis NN][colptr NN+8][btot 512][bptr 512][bcursor 512]
    // [srow E][pairs E*2]  -- pairs region later reused by xw0+y1
    // [hw0 NN*10][y2 NN*16]
    int*   degr    = (int*)d_ws;
    float* dis     = (float*)(degr + NN);
    int*   colptr  = (int*)(dis + NN);          // NN+1 used, NN+8 reserved
    int*   btot    = colptr + NN + 8;
    int*   bptr    = btot + 512;
    int*   bcursor = bptr + 512;
    int*   srow    = bcursor + 512;             // E ints
    int2*  pairs   = (int2*)(srow + E);         // E int2
    float* xw0     = (float*)pairs;             // alias: pairs dead after place2
    float* y1      = xw0 + (size_t)NN * HID;
    float* hw0     = (float*)(pairs + E);
    float* y2      = hw0 + (size_t)NN * NCLS;

    // output: [log_softmax NN*NCLS][x_latent NN*HID]
    float* out_ls = (float*)d_out;
    float* h      = out_ls + (size_t)NN * NCLS;

    hipMemsetAsync(degr, 0, NN * sizeof(int), stream);
    hipMemsetAsync(btot, 0, 512 * sizeof(int), stream);

    histA_kernel<<<1024, 256, 0, stream>>>(row, col, degr, btot, E);
    bscan_kernel<<<1, 512, 0, stream>>>(btot, bptr, bcursor, colptr);
    dis_kernel<<<(NN + 255) / 256, 256, 0, stream>>>(degr, dis);

    int chunk = (E + 511) / 512;
    bucket_kernel<<<512, 256, 0, stream>>>(row, col, bcursor, pairs, E, chunk);
    place2_kernel<<<NB, 256, 0, stream>>>(pairs, bptr, colptr, srow);

    mm1_kernel<<<(NN + 255) / 256, 256, 0, stream>>>(x, dis, W0_1, W1_1, b1, xw0, y1);
    gatherH_kernel<<<(NN + 3) / 4, 256, 0, stream>>>(colptr, srow, dis, y1, xw0, h);
    mm2_kernel<<<(NN + 255) / 256, 256, 0, stream>>>(h, dis, W0_2, W1_2, b2, hw0, y2);
    gatherOut_kernel<<<(NN + 3) / 4, 256, 0, stream>>>(colptr, srow, dis, y2, hw0, out_ls);
}

// Round 5
// 426.251 us; speedup vs baseline: 3.1429x; 1.2701x over previous
//
#include <hip/hip_runtime.h>

#define NN   100000
#define FIN  64
#define HID  32
#define NCLS 10
#define BW   256                    // destinations per bucket
#define NB   391                    // ceil(NN/BW)
#define HB   512                    // blocks in hist/bucket passes (same chunking!)

// ---------------------------------------------------------------------------
// hist2: chunked per-block LDS histograms of row-buckets and col-buckets.
// ghc/ghr layout: [bucket][block]  (bucket-major). No global atomics.
// ---------------------------------------------------------------------------
__global__ __launch_bounds__(256) void hist2_kernel(
        const int* __restrict__ row, const int* __restrict__ col,
        int* __restrict__ ghc, int* __restrict__ ghr, int E, int chunk) {
    __shared__ int lhc[NB], lhr[NB];
    for (int t = threadIdx.x; t < NB; t += 256) { lhc[t] = 0; lhr[t] = 0; }
    __syncthreads();
    int k = blockIdx.x;
    int base = k * chunk;
    int lim = base + chunk; if (lim > E) lim = E;
    for (int e = base + threadIdx.x; e < lim; e += 256) {
        int r = row[e], c = col[e];
        if (r != c) {
            atomicAdd(&lhc[c >> 8], 1);
            atomicAdd(&lhr[r >> 8], 1);
        }
    }
    __syncthreads();
    for (int t = threadIdx.x; t < NB; t += 256) {
        ghc[t * HB + k] = lhc[t];
        ghr[t * HB + k] = lhr[t];
    }
}

// ---------------------------------------------------------------------------
// coffs: per-bucket exclusive scan over the HB block-columns (in place) and
// per-bucket totals. One block per bucket, 512 threads.
// ---------------------------------------------------------------------------
__global__ __launch_bounds__(512) void coffs_kernel(
        int* __restrict__ ghc, int* __restrict__ ghr,
        int* __restrict__ ctot, int* __restrict__ rtot) {
    __shared__ int sh[HB];
    int b = blockIdx.x, t = threadIdx.x;
    int v = ghc[b * HB + t];
    sh[t] = v;
    __syncthreads();
    for (int off = 1; off < HB; off <<= 1) {
        int u = (t >= off) ? sh[t - off] : 0;
        __syncthreads(); sh[t] += u; __syncthreads();
    }
    ghc[b * HB + t] = sh[t] - v;
    if (t == HB - 1) ctot[b] = sh[t];
    __syncthreads();
    int w = ghr[b * HB + t];
    sh[t] = w;
    __syncthreads();
    for (int off = 1; off < HB; off <<= 1) {
        int u = (t >= off) ? sh[t - off] : 0;
        __syncthreads(); sh[t] += u; __syncthreads();
    }
    ghr[b * HB + t] = sh[t] - w;
    if (t == HB - 1) rtot[b] = sh[t];
}

// ---------------------------------------------------------------------------
// bscan: exclusive scan of the NB bucket totals (both keys).
// ---------------------------------------------------------------------------
__global__ __launch_bounds__(512) void bscan_kernel(
        const int* __restrict__ ctot, const int* __restrict__ rtot,
        int* __restrict__ cbptr, int* __restrict__ rbptr,
        int* __restrict__ colptr) {
    __shared__ int sh[512];
    int t = threadIdx.x;
    int v = (t < NB) ? ctot[t] : 0;
    sh[t] = v;
    __syncthreads();
    for (int off = 1; off < 512; off <<= 1) {
        int u = (t >= off) ? sh[t - off] : 0;
        __syncthreads(); sh[t] += u; __syncthreads();
    }
    if (t < NB) cbptr[t] = sh[t] - v;
    if (t == NB - 1) { cbptr[NB] = sh[t]; colptr[NN] = sh[t]; }
    __syncthreads();
    int w = (t < NB) ? rtot[t] : 0;
    sh[t] = w;
    __syncthreads();
    for (int off = 1; off < 512; off <<= 1) {
        int u = (t >= off) ? sh[t - off] : 0;
        __syncthreads(); sh[t] += u; __syncthreads();
    }
    if (t < NB) rbptr[t] = sh[t] - w;
    if (t == NB - 1) rbptr[NB] = sh[t];
}

// ---------------------------------------------------------------------------
// bucket2: deterministic bucketing, LDS cursors seeded from cbptr+ghc — zero
// global atomics. Writes packed (r<<8)|(c&255) by col-bucket and a 1-byte
// local-row stream by row-bucket.
// ---------------------------------------------------------------------------
__global__ __launch_bounds__(256) void bucket2_kernel(
        const int* __restrict__ row, const int* __restrict__ col,
        const int* __restrict__ ghc, const int* __restrict__ ghr,
        const int* __restrict__ cbptr, const int* __restrict__ rbptr,
        int* __restrict__ pk, unsigned char* __restrict__ rkb,
        int E, int chunk) {
    __shared__ int lcc[NB], lcr[NB];
    int k = blockIdx.x;
    for (int t = threadIdx.x; t < NB; t += 256) {
        lcc[t] = cbptr[t] + ghc[t * HB + k];
        lcr[t] = rbptr[t] + ghr[t * HB + k];
    }
    __syncthreads();
    int base = k * chunk;
    int lim = base + chunk; if (lim > E) lim = E;
    for (int e = base + threadIdx.x; e < lim; e += 256) {
        int r = row[e], c = col[e];
        if (r != c) {
            int pc = atomicAdd(&lcc[c >> 8], 1);
            pk[pc] = (r << 8) | (c & 255);
            int pr = atomicAdd(&lcr[r >> 8], 1);
            rkb[pr] = (unsigned char)(r & 255);
        }
    }
}

// ---------------------------------------------------------------------------
// countR: per-row-bucket LDS histogram of the byte stream -> dis[] directly.
// ---------------------------------------------------------------------------
__global__ __launch_bounds__(256) void countR_kernel(
        const unsigned char* __restrict__ rkb, const int* __restrict__ rbptr,
        float* __restrict__ dis) {
    __shared__ int cnt[BW];
    int b = blockIdx.x, t = threadIdx.x;
    cnt[t] = 0;
    __syncthreads();
    int s = rbptr[b], e = rbptr[b + 1];
    for (int i = s + t; i < e; i += 256) atomicAdd(&cnt[rkb[i]], 1);
    __syncthreads();
    int d = (b << 8) + t;
    if (d < NN) {
        int c = cnt[t];
        dis[d] = c > 0 ? rsqrtf((float)c) : 0.f;
    }
}

// ---------------------------------------------------------------------------
// place2: per-col-bucket LDS histogram + scan -> colptr; then place srow.
// ---------------------------------------------------------------------------
__global__ __launch_bounds__(256) void place2_kernel(
        const int* __restrict__ pk, const int* __restrict__ cbptr,
        int* __restrict__ colptr, int* __restrict__ srow) {
    __shared__ int lh[BW];
    __shared__ int incl[BW];
    __shared__ int lcur[BW];
    int b = blockIdx.x, t = threadIdx.x;
    int start = cbptr[b], end = cbptr[b + 1];
    lh[t] = 0;
    __syncthreads();
    for (int i = start + t; i < end; i += 256)
        atomicAdd(&lh[pk[i] & 255], 1);
    __syncthreads();
    int own = lh[t];
    incl[t] = own;
    __syncthreads();
    for (int off = 1; off < 256; off <<= 1) {
        int v = (t >= off) ? incl[t - off] : 0;
        __syncthreads(); incl[t] += v; __syncthreads();
    }
    int excl = start + incl[t] - own;
    int d = (b << 8) + t;
    if (d < NN) colptr[d] = excl;
    lcur[t] = excl;
    __syncthreads();
    for (int i = start + t; i < end; i += 256) {
        int p = pk[i];
        int pos = atomicAdd(&lcur[p & 255], 1);
        srow[pos] = p >> 8;
    }
}

// ---------------------------------------------------------------------------
// mm1: xw0 = x @ W0_1 + b1   and   y1 = dis[n] * (x @ W1_1)
// ---------------------------------------------------------------------------
__global__ __launch_bounds__(256) void mm1_kernel(
        const float* __restrict__ x, const float* __restrict__ dis,
        const float* __restrict__ W0, const float* __restrict__ W1,
        const float* __restrict__ b1, float* __restrict__ xw0,
        float* __restrict__ y1) {
    int n = blockIdx.x * 256 + threadIdx.x;
    if (n >= NN) return;
    float acc0[HID], acc1[HID];
#pragma unroll
    for (int j = 0; j < HID; ++j) { acc0[j] = b1[j]; acc1[j] = 0.f; }
    const float4* xr = (const float4*)(x + (size_t)n * FIN);
    for (int k4 = 0; k4 < FIN / 4; ++k4) {
        float4 xv = xr[k4];
        float xs[4] = {xv.x, xv.y, xv.z, xv.w};
#pragma unroll
        for (int kk = 0; kk < 4; ++kk) {
            const float* w0r = W0 + (k4 * 4 + kk) * HID;
            const float* w1r = W1 + (k4 * 4 + kk) * HID;
#pragma unroll
            for (int j = 0; j < HID; ++j) {
                acc0[j] += xs[kk] * w0r[j];
                acc1[j] += xs[kk] * w1r[j];
            }
        }
    }
    float dn = dis[n];
    float4* d0 = (float4*)(xw0 + (size_t)n * HID);
    float4* d1 = (float4*)(y1 + (size_t)n * HID);
#pragma unroll
    for (int j4 = 0; j4 < HID / 4; ++j4) {
        d0[j4] = make_float4(acc0[j4*4], acc0[j4*4+1], acc0[j4*4+2], acc0[j4*4+3]);
        d1[j4] = make_float4(dn*acc1[j4*4], dn*acc1[j4*4+1], dn*acc1[j4*4+2], dn*acc1[j4*4+3]);
    }
}

// ---------------------------------------------------------------------------
// gatherH: h[c] = relu(xw0[c] - dis[c] * sum_{r in N(c)} y1[r])
// ---------------------------------------------------------------------------
__global__ __launch_bounds__(256) void gatherH_kernel(
        const int* __restrict__ colptr, const int* __restrict__ srow,
        const float* __restrict__ dis, const float* __restrict__ y1,
        const float* __restrict__ xw0, float* __restrict__ h) {
    int lane = threadIdx.x & 63;
    int sub = lane >> 5, f = lane & 31;
    int c = __builtin_amdgcn_readfirstlane(blockIdx.x * 4 + (threadIdx.x >> 6));
    if (c >= NN) return;
    int start = colptr[c], end = colptr[c + 1];
    float a0 = 0.f, a1 = 0.f;
    int i = start + sub;
    for (; i + 2 < end; i += 4) {
        int r0 = srow[i], r1 = srow[i + 2];
        a0 += y1[(size_t)r0 * HID + f];
        a1 += y1[(size_t)r1 * HID + f];
    }
    for (; i < end; i += 2) a0 += y1[(size_t)srow[i] * HID + f];
    float tot = a0 + a1;
    tot += __shfl_xor(tot, 32);
    if (lane < 32) {
        float v = xw0[(size_t)c * HID + f] - dis[c] * tot;
        h[(size_t)c * HID + f] = fmaxf(v, 0.f);
    }
}

// ---------------------------------------------------------------------------
// mm2: hw0 = h @ W0_2 + b2  [NN,10]  and  y2 = dis[n]*(h @ W1_2) padded to 16
// ---------------------------------------------------------------------------
__global__ __launch_bounds__(256) void mm2_kernel(
        const float* __restrict__ h, const float* __restrict__ dis,
        const float* __restrict__ W0, const float* __restrict__ W1,
        const float* __restrict__ b2, float* __restrict__ hw0,
        float* __restrict__ y2) {
    int n = blockIdx.x * 256 + threadIdx.x;
    if (n >= NN) return;
    float acc0[NCLS], acc1[NCLS];
#pragma unroll
    for (int j = 0; j < NCLS; ++j) { acc0[j] = b2[j]; acc1[j] = 0.f; }
    const float4* hr = (const float4*)(h + (size_t)n * HID);
#pragma unroll
    for (int k4 = 0; k4 < HID / 4; ++k4) {
        float4 hv = hr[k4];
        float hs[4] = {hv.x, hv.y, hv.z, hv.w};
#pragma unroll
        for (int kk = 0; kk < 4; ++kk) {
            const float* w0r = W0 + (k4 * 4 + kk) * NCLS;
            const float* w1r = W1 + (k4 * 4 + kk) * NCLS;
#pragma unroll
            for (int j = 0; j < NCLS; ++j) {
                acc0[j] += hs[kk] * w0r[j];
                acc1[j] += hs[kk] * w1r[j];
            }
        }
    }
    float dn = dis[n];
    float* hd = hw0 + (size_t)n * NCLS;
#pragma unroll
    for (int j = 0; j < NCLS; ++j) hd[j] = acc0[j];
    float4* yd = (float4*)(y2 + (size_t)n * 16);
    float v[16];
#pragma unroll
    for (int j = 0; j < NCLS; ++j) v[j] = dn * acc1[j];
#pragma unroll
    for (int j = NCLS; j < 16; ++j) v[j] = 0.f;
#pragma unroll
    for (int j4 = 0; j4 < 4; ++j4)
        yd[j4] = make_float4(v[j4*4], v[j4*4+1], v[j4*4+2], v[j4*4+3]);
}

// ---------------------------------------------------------------------------
// gatherOut: out[c] = log_softmax(hw0[c] - dis[c]*sum y2[r])
// ---------------------------------------------------------------------------
__global__ __launch_bounds__(256) void gatherOut_kernel(
        const int* __restrict__ colptr, const int* __restrict__ srow,
        const float* __restrict__ dis, const float* __restrict__ y2,
        const float* __restrict__ hw0, float* __restrict__ out) {
    int lane = threadIdx.x & 63;
    int sub = lane >> 4, f = lane & 15;
    int c = __builtin_amdgcn_readfirstlane(blockIdx.x * 4 + (threadIdx.x >> 6));
    if (c >= NN) return;
    int start = colptr[c], end = colptr[c + 1];
    float a0 = 0.f, a1 = 0.f;
    int i = start + sub;
    for (; i + 4 < end; i += 8) {
        int r0 = srow[i], r1 = srow[i + 4];
        a0 += y2[(size_t)r0 * 16 + f];
        a1 += y2[(size_t)r1 * 16 + f];
    }
    for (; i < end; i += 4) a0 += y2[(size_t)srow[i] * 16 + f];
    float tot = a0 + a1;
    tot += __shfl_xor(tot, 16);
    tot += __shfl_xor(tot, 32);
    float val = (f < NCLS ? hw0[(size_t)c * NCLS + f] : 0.f) - dis[c] * tot;
    float mv = (f < NCLS) ? val : -INFINITY;
    mv = fmaxf(mv, __shfl_xor(mv, 1));
    mv = fmaxf(mv, __shfl_xor(mv, 2));
    mv = fmaxf(mv, __shfl_xor(mv, 4));
    mv = fmaxf(mv, __shfl_xor(mv, 8));
    float ev = (f < NCLS) ? expf(val - mv) : 0.f;
    ev += __shfl_xor(ev, 1);
    ev += __shfl_xor(ev, 2);
    ev += __shfl_xor(ev, 4);
    ev += __shfl_xor(ev, 8);
    float lse = mv + logf(ev);
    if (lane < 16 && f < NCLS) out[(size_t)c * NCLS + f] = val - lse;
}

// ---------------------------------------------------------------------------
extern "C" void kernel_launch(void* const* d_in, const int* in_sizes, int n_in,
                              void* d_out, int out_size, void* d_ws, size_t ws_size,
                              hipStream_t stream) {
    const float* x    = (const float*)d_in[0];
    const int*   ei   = (const int*)d_in[1];
    const float* W0_1 = (const float*)d_in[2];
    const float* W1_1 = (const float*)d_in[3];
    const float* b1   = (const float*)d_in[4];
    const float* W0_2 = (const float*)d_in[5];
    const float* W1_2 = (const float*)d_in[6];
    const float* b2   = (const float*)d_in[7];

    const int E = in_sizes[1] / 2;
    const int* row = ei;
    const int* col = ei + E;

    // workspace layout (ints, 16B-aligned):
    // [colptr NN+8][dis NN][cbptr 512][rbptr 512][ctot 512][rtot 512]
    // [srow E]
    // region C (reused): phase1 = [ghc NB*HB][ghr NB*HB][pk E][rkb E/4]
    //                    phase2 = [xw0 NN*HID][y1 NN*HID][hw0 NN*NCLS][y2 NN*16]
    int*   colptr = (int*)d_ws;
    float* dis    = (float*)(colptr + NN + 8);
    int*   cbptr  = (int*)(dis + NN);
    int*   rbptr  = cbptr + 512;
    int*   ctot   = rbptr + 512;
    int*   rtot   = ctot + 512;
    int*   srow   = rtot + 512;
    int*   C      = srow + E;
    int*   ghc    = C;
    int*   ghr    = ghc + NB * HB;
    int*   pk     = ghr + NB * HB;
    unsigned char* rkb = (unsigned char*)(pk + E);
    float* xw0    = (float*)C;
    float* y1     = xw0 + (size_t)NN * HID;
    float* hw0    = y1 + (size_t)NN * HID;
    float* y2     = hw0 + (size_t)NN * NCLS;

    // output: [log_softmax NN*NCLS][x_latent NN*HID]
    float* out_ls = (float*)d_out;
    float* h      = out_ls + (size_t)NN * NCLS;

    int chunk = (E + HB - 1) / HB;

    hist2_kernel<<<HB, 256, 0, stream>>>(row, col, ghc, ghr, E, chunk);
    coffs_kernel<<<NB, 512, 0, stream>>>(ghc, ghr, ctot, rtot);
    bscan_kernel<<<1, 512, 0, stream>>>(ctot, rtot, cbptr, rbptr, colptr);
    bucket2_kernel<<<HB, 256, 0, stream>>>(row, col, ghc, ghr, cbptr, rbptr,
                                           pk, rkb, E, chunk);
    countR_kernel<<<NB, 256, 0, stream>>>(rkb, rbptr, dis);
    place2_kernel<<<NB, 256, 0, stream>>>(pk, cbptr, colptr, srow);

    mm1_kernel<<<(NN + 255) / 256, 256, 0, stream>>>(x, dis, W0_1, W1_1, b1, xw0, y1);
    gatherH_kernel<<<(NN + 3) / 4, 256, 0, stream>>>(colptr, srow, dis, y1, xw0, h);
    mm2_kernel<<<(NN + 255) / 256, 256, 0, stream>>>(h, dis, W0_2, W1_2, b2, hw0, y2);
    gatherOut_kernel<<<(NN + 3) / 4, 256, 0, stream>>>(colptr, srow, dis, y2, hw0, out_ls);
}